// Round 11
// baseline (263.639 us; speedup 1.0000x reference)
//
#include <hip/hip_runtime.h>

#define HD 1024
#define BB 64
#define II 512

typedef float f4 __attribute__((ext_vector_type(4)));

__device__ __forceinline__ float fast_tanh(float x) {
    float ax = __builtin_fabsf(x);
    float e  = __builtin_amdgcn_exp2f(ax * -2.8853900817779268f);  // exp(-2|x|)
    float t  = (1.0f - e) * __builtin_amdgcn_rcpf(1.0f + e);
    return x < 0.0f ? -t : t;
}

// out[b][h] = tanh( sum_k A[b][k] * W[h][k] + bias[h] )
// Block = 1024 thr = 16 waves = 16 b's sharing one h-octet staged in LDS.
// grid 512 = 128 octets x 4 b-groups.
template <int K>
__global__ __launch_bounds__(1024) void k_gemm(const float* __restrict__ A,    // [64][K]
                                               const float* __restrict__ W,    // [1024][K]
                                               const float* __restrict__ bias, // [1024]
                                               float* __restrict__ out)        // [64][1024]
{
    constexpr int J = K / 256;
    __shared__ float wlds[8 * K];

    int tid  = threadIdx.x;
    int oct  = blockIdx.x & 127;
    int bg   = blockIdx.x >> 7;          // 0..3
    int h0   = oct * 8;

    {
        const f4* src = (const f4*)(W + (size_t)h0 * K);
        f4* dst = (f4*)wlds;
#pragma unroll
        for (int v = tid; v < 2 * K; v += 1024) dst[v] = src[v];
    }
    __syncthreads();

    int lane = tid & 63;
    int wave = tid >> 6;
    int b    = bg * 16 + wave;

    f4 a[J];
#pragma unroll
    for (int j = 0; j < J; ++j)
        a[j] = *(const f4*)(A + (size_t)b * K + j * 256 + lane * 4);

    float acc[8];
#pragma unroll
    for (int hh = 0; hh < 8; ++hh) {
        const float* wrow = wlds + hh * K;
        float s = 0.f;
#pragma unroll
        for (int j = 0; j < J; ++j) {
            f4 w4 = *(const f4*)(wrow + j * 256 + lane * 4);
            s += a[j].x * w4.x + a[j].y * w4.y + a[j].z * w4.z + a[j].w * w4.w;
        }
        acc[hh] = s;
    }
#pragma unroll
    for (int hh = 0; hh < 8; ++hh)
#pragma unroll
        for (int off = 32; off; off >>= 1)
            acc[hh] += __shfl_xor(acc[hh], off, 64);
    if (lane == 0) {
        f4 o0, o1;
        o0.x = fast_tanh(acc[0] + bias[h0 + 0]);
        o0.y = fast_tanh(acc[1] + bias[h0 + 1]);
        o0.z = fast_tanh(acc[2] + bias[h0 + 2]);
        o0.w = fast_tanh(acc[3] + bias[h0 + 3]);
        o1.x = fast_tanh(acc[4] + bias[h0 + 4]);
        o1.y = fast_tanh(acc[5] + bias[h0 + 5]);
        o1.z = fast_tanh(acc[6] + bias[h0 + 6]);
        o1.w = fast_tanh(acc[7] + bias[h0 + 7]);
        *(f4*)(out + (size_t)b * HD + h0)     = o0;
        *(f4*)(out + (size_t)b * HD + h0 + 4) = o1;
    }
}

// Grouped plastic (32 b's): grid 1024 = 8 bg x 128 hg, 512 thr = 8 waves.
// Wave owns h, holds alpha/Wfc2 rows in regs, loops 4 b's; x rows in LDS.
// Innate computed inline. pw loads REGULAR -> allocate in L3 for update_g.
__global__ __launch_bounds__(512) void k_plastic(const float* __restrict__ pw,
                                                 const float* __restrict__ alpha,
                                                 const float* __restrict__ Wfc2,
                                                 const float* __restrict__ bfc2,
                                                 const float* __restrict__ x,      // [64][1024]
                                                 float* __restrict__ pre,          // [64][1024]
                                                 float* __restrict__ hidden,       // [64][1024]
                                                 int b0grp)
{
    __shared__ float xs[4][HD];          // 16 KB
    int tid  = threadIdx.x;
    int lane = tid & 63;
    int wave = tid >> 6;
    int bg   = blockIdx.x >> 7;          // 0..7
    int hg   = blockIdx.x & 127;
    int b0   = b0grp + bg * 4;
    int h    = hg * 8 + wave;

#pragma unroll
    for (int v = tid; v < 1024; v += 512) {
        int r = v >> 8, c = (v & 255) * 4;
        *(f4*)&xs[r][c] = *(const f4*)(x + ((b0 + r) << 10) + c);
    }
    __syncthreads();

    const float* ar = alpha + ((size_t)h << 10);
    const float* wr = Wfc2 + ((size_t)h << 10);
    f4 av[4], wv[4];
#pragma unroll
    for (int j = 0; j < 4; ++j) {
        av[j] = *(const f4*)(ar + j * 256 + lane * 4);
        wv[j] = *(const f4*)(wr + j * 256 + lane * 4);
    }
    float bfc = bfc2[h];

#pragma unroll
    for (int bb = 0; bb < 4; ++bb) {
        const float* prow = pw + ((size_t)(b0 + bb) << 20) + ((size_t)h << 10);
        float accp = 0.f, acci = 0.f;
#pragma unroll
        for (int j = 0; j < 4; ++j) {
            f4 p4 = *(const f4*)(prow + j * 256 + lane * 4);
            f4 x4 = *(const f4*)&xs[bb][j * 256 + lane * 4];
            accp += av[j].x * p4.x * x4.x + av[j].y * p4.y * x4.y +
                    av[j].z * p4.z * x4.z + av[j].w * p4.w * x4.w;
            acci += wv[j].x * x4.x + wv[j].y * x4.y + wv[j].z * x4.z + wv[j].w * x4.w;
        }
#pragma unroll
        for (int off = 32; off; off >>= 1) {
            accp += __shfl_xor(accp, off, 64);
            acci += __shfl_xor(acci, off, 64);
        }
        if (lane == 0) {
            float pv = acci + bfc + accp;
            pre[((b0 + bb) << 10) + h]    = pv;
            hidden[((b0 + bb) << 10) + h] = fast_tanh(pv);
        }
    }
}

// Grouped heads (32 b's): grid 32 x 1024 thr. Full Whr GEMV + nm/choice/value
// per b in one block; fixed-order final reduce -> deterministic.
__global__ __launch_bounds__(1024) void k_heads(const float* __restrict__ hidden, // [64][1024]
                                                const float* __restrict__ reward, // [64]
                                                const float* __restrict__ Wr,     // [1024]
                                                const float* __restrict__ br,     // [1024]
                                                const float* __restrict__ Whr,
                                                const float* __restrict__ bhr,
                                                const float* __restrict__ Wnm,
                                                const float* __restrict__ bnm,
                                                const float* __restrict__ Wch,
                                                const float* __restrict__ bch,
                                                const float* __restrict__ Wv,
                                                const float* __restrict__ bv,
                                                float* __restrict__ out_choice,
                                                float* __restrict__ out_nm,
                                                float* __restrict__ out_value,
                                                int b0grp)
{
    __shared__ float hplus[HD];
    __shared__ float wred[16][4];
    int tid  = threadIdx.x;
    int lane = tid & 63;
    int wave = tid >> 6;           // 0..15
    int b    = b0grp + blockIdx.x;

    hplus[tid] = hidden[(b << 10) + tid] + reward[b] * Wr[tid] + br[tid];
    __syncthreads();

    float nm0 = 0.f, nm1 = 0.f;
#pragma unroll 1
    for (int rp = 0; rp < 32; ++rp) {
        int h2 = (wave << 6) + (rp << 1);
        const float* w0 = Whr + ((size_t)h2 << 10);
        const float* w1 = w0 + HD;
        float s0 = 0.f, s1 = 0.f;
#pragma unroll
        for (int j = 0; j < 4; ++j) {
            int i = j * 256 + lane * 4;
            f4 wa = *(const f4*)(w0 + i);
            f4 wb = *(const f4*)(w1 + i);
            f4 h4 = *(const f4*)(hplus + i);
            s0 += wa.x * h4.x + wa.y * h4.y + wa.z * h4.z + wa.w * h4.w;
            s1 += wb.x * h4.x + wb.y * h4.y + wb.z * h4.z + wb.w * h4.w;
        }
#pragma unroll
        for (int off = 32; off; off >>= 1) {
            s0 += __shfl_xor(s0, off, 64);
            s1 += __shfl_xor(s1, off, 64);
        }
        if (lane == 0) {
            float hr0 = fast_tanh(s0 + bhr[h2]);
            float hr1 = fast_tanh(s1 + bhr[h2 + 1]);
            nm0 += Wnm[h2] * hr0 + Wnm[h2 + 1] * hr1;
            nm1 += Wnm[HD + h2] * hr0 + Wnm[HD + h2 + 1] * hr1;
        }
    }
    int idx = (wave << 6) + lane;
    float hv = hidden[(b << 10) + idx];
    float cv = Wch[idx] * hv;
    float vv = Wv[idx] * hv;
#pragma unroll
    for (int off = 32; off; off >>= 1) {
        cv += __shfl_xor(cv, off, 64);
        vv += __shfl_xor(vv, off, 64);
    }
    if (lane == 0) {
        wred[wave][0] = nm0; wred[wave][1] = nm1;
        wred[wave][2] = cv;  wred[wave][3] = vv;
    }
    __syncthreads();
    if (tid == 0) {
        float s0 = 0.f, s1 = 0.f, s2 = 0.f, s3 = 0.f;
        for (int w = 0; w < 16; ++w) {          // fixed order -> deterministic
            s0 += wred[w][0]; s1 += wred[w][1];
            s2 += wred[w][2]; s3 += wred[w][3];
        }
        float n0 = fast_tanh(s0 + bnm[0]);
        float n1 = fast_tanh(s1 + bnm[1]);
        out_nm[b] = n0 - n1;
        float z = s2 + bch[0];
        out_choice[b] = __builtin_amdgcn_rcpf(1.0f + __builtin_amdgcn_exp2f(-z * 1.4426950408889634f));
        out_value[b]  = s3 + bv[0];
    }
}

// Grouped update (32 b's = 128 MB, fully L3-resident after plastic_g).
// grid 4096 x 256 thr x 8 f4. REGULAR pw loads (take the L3 hits!), NT stores.
// Reverse traversal: freshest-written pw tiles first.
__global__ __launch_bounds__(256) void k_update(const float* __restrict__ pw,
                                                const float* __restrict__ pre, // [64][1024]
                                                const float* __restrict__ x,   // [64][1024]
                                                const float* __restrict__ nm,  // [64]
                                                float* __restrict__ out,
                                                int b0grp) {
    const int stride = 4096 * 256;       // 1,048,576 f4 per stripe
    int blk = 4095 - (int)blockIdx.x;
#pragma unroll
    for (int it = 7; it >= 0; --it) {
        int f = blk * 256 + threadIdx.x + it * stride;   // 0..8,388,607
        int b = b0grp + (f >> 18);                       // 256K f4 per b
        size_t e = ((size_t)b << 20) + (((size_t)(f & 0x3FFFF)) << 2);
        int h = (f >> 8) & 1023;
        int i = (f & 255) << 2;
        f4 p4 = *(const f4*)(pw + e);
        f4 x4 = *(const f4*)(x + (b << 10) + i);
        float ps = pre[(b << 10) + h];
        float nb = nm[b];
        f4 o4;
        o4.x = fminf(fmaxf(p4.x + nb * fast_tanh(ps * x4.x), -50.f), 50.f);
        o4.y = fminf(fmaxf(p4.y + nb * fast_tanh(ps * x4.y), -50.f), 50.f);
        o4.z = fminf(fmaxf(p4.z + nb * fast_tanh(ps * x4.z), -50.f), 50.f);
        o4.w = fminf(fmaxf(p4.w + nb * fast_tanh(ps * x4.w), -50.f), 50.f);
        __builtin_nontemporal_store(o4, (f4*)(out + e));
    }
}

extern "C" void kernel_launch(void* const* d_in, const int* in_sizes, int n_in,
                              void* d_out, int out_size, void* d_ws, size_t ws_size,
                              hipStream_t stream) {
    const float* items  = (const float*)d_in[0];
    const float* pw     = (const float*)d_in[1];
    const float* reward = (const float*)d_in[2];
    const float* We     = (const float*)d_in[3];
    const float* be     = (const float*)d_in[4];
    const float* W1     = (const float*)d_in[5];
    const float* b1     = (const float*)d_in[6];
    const float* W2     = (const float*)d_in[7];
    const float* b2     = (const float*)d_in[8];
    const float* Wfc2   = (const float*)d_in[9];
    const float* bfc2   = (const float*)d_in[10];
    const float* Whr    = (const float*)d_in[11];
    const float* bhr    = (const float*)d_in[12];
    const float* Wch    = (const float*)d_in[13];
    const float* bch    = (const float*)d_in[14];
    const float* Wr     = (const float*)d_in[15];
    const float* br     = (const float*)d_in[16];
    const float* Wnm    = (const float*)d_in[17];
    const float* bnm    = (const float*)d_in[18];
    const float* alpha  = (const float*)d_in[19];
    const float* Wv     = (const float*)d_in[20];
    const float* bv     = (const float*)d_in[21];

    float* ws   = (float*)d_ws;
    float* x0   = ws;                // 65536
    float* x1   = ws + 65536;        // 65536
    float* x2   = ws + 131072;       // 65536
    float* preb = ws + 196608;       // 65536

    float* out        = (float*)d_out;
    float* out_choice = out;                        // 64
    float* out_nm     = out + 64;                   // 64
    float* out_value  = out + 128;                  // 64
    float* out_newpw  = out + 192;                  // 67,108,864
    float* out_hidden = out + 192 + BB * HD * HD;   // 65,536

    k_gemm<II><<<512, 1024, 0, stream>>>(items, We, be, x0);
    k_gemm<HD><<<512, 1024, 0, stream>>>(x0, W1, b1, x1);
    k_gemm<HD><<<512, 1024, 0, stream>>>(x1, W2, b2, x2);

    for (int g = 0; g < 2; ++g) {
        int b0 = g * 32;
        k_plastic<<<1024, 512, 0, stream>>>(pw, alpha, Wfc2, bfc2, x2, preb, out_hidden, b0);
        k_heads<<<32, 1024, 0, stream>>>(out_hidden, reward, Wr, br, Whr, bhr,
                                         Wnm, bnm, Wch, bch, Wv, bv,
                                         out_choice, out_nm, out_value, b0);
        k_update<<<4096, 256, 0, stream>>>(pw, preb, x2, out_nm, out_newpw, b0);
    }
}

// Round 12
// 194.078 us; speedup vs baseline: 1.3584x; 1.3584x over previous
//
#include <hip/hip_runtime.h>

#define HD 1024
#define BB 64
#define II 512

typedef float f4 __attribute__((ext_vector_type(4)));

__device__ __forceinline__ float fast_tanh(float x) {
    float ax = __builtin_fabsf(x);
    float e  = __builtin_amdgcn_exp2f(ax * -2.8853900817779268f);  // exp(-2|x|)
    float t  = (1.0f - e) * __builtin_amdgcn_rcpf(1.0f + e);
    return x < 0.0f ? -t : t;
}

// out[b][h] = tanh( sum_k A[b][k] * W[h][k] + bias[h] )
// Block = 1024 thr = 16 waves = 16 b's sharing one h-octet staged in LDS.
// grid 512 = 128 octets x 4 b-groups.
template <int K>
__global__ __launch_bounds__(1024) void k_gemm(const float* __restrict__ A,    // [64][K]
                                               const float* __restrict__ W,    // [1024][K]
                                               const float* __restrict__ bias, // [1024]
                                               float* __restrict__ out)        // [64][1024]
{
    constexpr int J = K / 256;
    __shared__ float wlds[8 * K];

    int tid  = threadIdx.x;
    int oct  = blockIdx.x & 127;
    int bg   = blockIdx.x >> 7;          // 0..3
    int h0   = oct * 8;

    {
        const f4* src = (const f4*)(W + (size_t)h0 * K);
        f4* dst = (f4*)wlds;
#pragma unroll
        for (int v = tid; v < 2 * K; v += 1024) dst[v] = src[v];
    }
    __syncthreads();

    int lane = tid & 63;
    int wave = tid >> 6;
    int b    = bg * 16 + wave;

    f4 a[J];
#pragma unroll
    for (int j = 0; j < J; ++j)
        a[j] = *(const f4*)(A + (size_t)b * K + j * 256 + lane * 4);

    float acc[8];
#pragma unroll
    for (int hh = 0; hh < 8; ++hh) {
        const float* wrow = wlds + hh * K;
        float s = 0.f;
#pragma unroll
        for (int j = 0; j < J; ++j) {
            f4 w4 = *(const f4*)(wrow + j * 256 + lane * 4);
            s += a[j].x * w4.x + a[j].y * w4.y + a[j].z * w4.z + a[j].w * w4.w;
        }
        acc[hh] = s;
    }
#pragma unroll
    for (int hh = 0; hh < 8; ++hh)
#pragma unroll
        for (int off = 32; off; off >>= 1)
            acc[hh] += __shfl_xor(acc[hh], off, 64);
    if (lane == 0) {
        f4 o0, o1;
        o0.x = fast_tanh(acc[0] + bias[h0 + 0]);
        o0.y = fast_tanh(acc[1] + bias[h0 + 1]);
        o0.z = fast_tanh(acc[2] + bias[h0 + 2]);
        o0.w = fast_tanh(acc[3] + bias[h0 + 3]);
        o1.x = fast_tanh(acc[4] + bias[h0 + 4]);
        o1.y = fast_tanh(acc[5] + bias[h0 + 5]);
        o1.z = fast_tanh(acc[6] + bias[h0 + 6]);
        o1.w = fast_tanh(acc[7] + bias[h0 + 7]);
        *(f4*)(out + (size_t)b * HD + h0)     = o0;
        *(f4*)(out + (size_t)b * HD + h0 + 4) = o1;
    }
}

// Grouped plastic (32 b's): grid 512 = 4 bg x 128 hg, 512 thr = 8 waves.
// Wave owns h, holds alpha/Wfc2 rows in regs, loops 8 b's; x rows in LDS.
// Innate inline. pw loads REGULAR -> allocate in L3 for update_g.
__global__ __launch_bounds__(512) void k_plastic(const float* __restrict__ pw,
                                                 const float* __restrict__ alpha,
                                                 const float* __restrict__ Wfc2,
                                                 const float* __restrict__ bfc2,
                                                 const float* __restrict__ x,      // [64][1024]
                                                 float* __restrict__ pre,          // [64][1024]
                                                 float* __restrict__ hidden,       // [64][1024]
                                                 int b0grp)
{
    __shared__ float xs[8][HD];          // 32 KB
    int tid  = threadIdx.x;
    int lane = tid & 63;
    int wave = tid >> 6;
    int bg   = blockIdx.x >> 7;          // 0..3
    int hg   = blockIdx.x & 127;
    int b0   = b0grp + bg * 8;
    int h    = hg * 8 + wave;

#pragma unroll
    for (int v = tid; v < 2048; v += 512) {
        int r = v >> 8, c = (v & 255) * 4;
        *(f4*)&xs[r][c] = *(const f4*)(x + ((b0 + r) << 10) + c);
    }
    __syncthreads();

    const float* ar = alpha + ((size_t)h << 10);
    const float* wr = Wfc2 + ((size_t)h << 10);
    f4 av[4], wv[4];
#pragma unroll
    for (int j = 0; j < 4; ++j) {
        av[j] = *(const f4*)(ar + j * 256 + lane * 4);
        wv[j] = *(const f4*)(wr + j * 256 + lane * 4);
    }
    float bfc = bfc2[h];

#pragma unroll
    for (int bb = 0; bb < 8; ++bb) {
        const float* prow = pw + ((size_t)(b0 + bb) << 20) + ((size_t)h << 10);
        float accp = 0.f, acci = 0.f;
#pragma unroll
        for (int j = 0; j < 4; ++j) {
            f4 p4 = *(const f4*)(prow + j * 256 + lane * 4);
            f4 x4 = *(const f4*)&xs[bb][j * 256 + lane * 4];
            accp += av[j].x * p4.x * x4.x + av[j].y * p4.y * x4.y +
                    av[j].z * p4.z * x4.z + av[j].w * p4.w * x4.w;
            acci += wv[j].x * x4.x + wv[j].y * x4.y + wv[j].z * x4.z + wv[j].w * x4.w;
        }
#pragma unroll
        for (int off = 32; off; off >>= 1) {
            accp += __shfl_xor(accp, off, 64);
            acci += __shfl_xor(acci, off, 64);
        }
        if (lane == 0) {
            float pv = acci + bfc + accp;
            pre[((b0 + bb) << 10) + h]    = pv;
            hidden[((b0 + bb) << 10) + h] = fast_tanh(pv);
        }
    }
}

// Grouped hrc+nm partials (16 b's per block-column, 32 b's total):
// grid 256 = 128 oct x 2 bg, 1024 thr = 16 waves = 16 b's. Whr octet + Wr + br
// staged in LDS. Wave computes 8 hrc values for its b, then the octet's partial
// nm dot -> parts[b][oct] (fixed order finalize later).
__global__ __launch_bounds__(1024) void k_hrcnm(const float* __restrict__ hidden, // [64][1024]
                                                const float* __restrict__ reward, // [64]
                                                const float* __restrict__ Wr,     // [1024]
                                                const float* __restrict__ br,     // [1024]
                                                const float* __restrict__ Whr,
                                                const float* __restrict__ bhr,
                                                const float* __restrict__ Wnm,    // [2][1024]
                                                float2* __restrict__ parts,       // [64][128]
                                                int b0grp)
{
    __shared__ float wlds[10 * HD];      // 8 Whr rows + Wr + br = 40 KB
    int tid  = threadIdx.x;
    int oct  = blockIdx.x >> 1;          // 0..127
    int bg   = blockIdx.x & 1;           // 0..1
    int h0   = oct * 8;

    {
        const f4* src = (const f4*)(Whr + (size_t)h0 * HD);
        f4* dst = (f4*)wlds;
#pragma unroll
        for (int v = tid; v < 2 * HD; v += 1024) dst[v] = src[v];
        const f4* wrs = (const f4*)Wr;
        const f4* brs = (const f4*)br;
        f4* d2 = (f4*)(wlds + 8 * HD);
        f4* d3 = (f4*)(wlds + 9 * HD);
        if (tid < 256) {
            d2[tid] = wrs[tid];
            d3[tid] = brs[tid];
        }
    }
    __syncthreads();

    int lane = tid & 63;
    int wave = tid >> 6;
    int b    = b0grp + bg * 16 + wave;
    float rb = reward[b];

    f4 a[4];
#pragma unroll
    for (int j = 0; j < 4; ++j) {
        int i = j * 256 + lane * 4;
        f4 h4  = *(const f4*)(hidden + (size_t)b * HD + i);
        f4 wr4 = *(const f4*)(wlds + 8 * HD + i);
        f4 br4 = *(const f4*)(wlds + 9 * HD + i);
        a[j].x = h4.x + rb * wr4.x + br4.x;
        a[j].y = h4.y + rb * wr4.y + br4.y;
        a[j].z = h4.z + rb * wr4.z + br4.z;
        a[j].w = h4.w + rb * wr4.w + br4.w;
    }
    float acc[8];
#pragma unroll
    for (int hh = 0; hh < 8; ++hh) {
        const float* wrow = wlds + hh * HD;
        float s = 0.f;
#pragma unroll
        for (int j = 0; j < 4; ++j) {
            f4 w4 = *(const f4*)(wrow + j * 256 + lane * 4);
            s += a[j].x * w4.x + a[j].y * w4.y + a[j].z * w4.z + a[j].w * w4.w;
        }
        acc[hh] = s;
    }
#pragma unroll
    for (int hh = 0; hh < 8; ++hh)
#pragma unroll
        for (int off = 32; off; off >>= 1)
            acc[hh] += __shfl_xor(acc[hh], off, 64);
    if (lane == 0) {
        float p0 = 0.f, p1 = 0.f;
#pragma unroll
        for (int hh = 0; hh < 8; ++hh) {
            float hr = fast_tanh(acc[hh] + bhr[h0 + hh]);
            p0 += Wnm[h0 + hh] * hr;
            p1 += Wnm[HD + h0 + hh] * hr;
        }
        parts[(b << 7) + oct] = make_float2(p0, p1);
    }
}

// Grouped finalize (32 b's): grid 32 x 256 thr. Fixed-order parts sum -> nm;
// choice/value dots from hidden.
__global__ __launch_bounds__(256) void k_fin(const float* __restrict__ hidden,
                                             const float2* __restrict__ parts,  // [64][128]
                                             const float* __restrict__ Wnmb,    // bnm [2]
                                             const float* __restrict__ Wch,
                                             const float* __restrict__ bch,
                                             const float* __restrict__ Wv,
                                             const float* __restrict__ bv,
                                             float* __restrict__ out_choice,
                                             float* __restrict__ out_nm,
                                             float* __restrict__ out_value,
                                             int b0grp)
{
    __shared__ float2 pl[128];
    __shared__ float wred[4][2];
    int tid = threadIdx.x;
    int b   = b0grp + blockIdx.x;

    if (tid < 128) pl[tid] = parts[(b << 7) + tid];

    int lane = tid & 63, wave = tid >> 6;
    int idx = tid * 4;
    f4 h4 = *(const f4*)(hidden + (size_t)b * HD + idx);
    f4 c4 = *(const f4*)(Wch + idx);
    f4 v4 = *(const f4*)(Wv + idx);
    float cv = c4.x * h4.x + c4.y * h4.y + c4.z * h4.z + c4.w * h4.w;
    float vv = v4.x * h4.x + v4.y * h4.y + v4.z * h4.z + v4.w * h4.w;
#pragma unroll
    for (int off = 32; off; off >>= 1) {
        cv += __shfl_xor(cv, off, 64);
        vv += __shfl_xor(vv, off, 64);
    }
    if (lane == 0) { wred[wave][0] = cv; wred[wave][1] = vv; }
    __syncthreads();
    if (tid == 0) {
        float s0 = 0.f, s1 = 0.f;
        for (int q = 0; q < 128; ++q) {       // fixed order -> deterministic
            s0 += pl[q].x; s1 += pl[q].y;
        }
        float n0 = fast_tanh(s0 + Wnmb[0]);
        float n1 = fast_tanh(s1 + Wnmb[1]);
        out_nm[b] = n0 - n1;
        float c = wred[0][0] + wred[1][0] + wred[2][0] + wred[3][0];
        float v = wred[0][1] + wred[1][1] + wred[2][1] + wred[3][1];
        float z = c + bch[0];
        out_choice[b] = __builtin_amdgcn_rcpf(1.0f + __builtin_amdgcn_exp2f(-z * 1.4426950408889634f));
        out_value[b]  = v + bv[0];
    }
}

// Grouped update (32 b's = 128 MB). grid 4096 x 256 thr x 8 f4.
// REVERSE traversal (freshest plastic lines first), REGULAR pw loads (take the
// L3 hits), NT stores (don't evict pw with the write stream).
__global__ __launch_bounds__(256) void k_update(const float* __restrict__ pw,
                                                const float* __restrict__ pre, // [64][1024]
                                                const float* __restrict__ x,   // [64][1024]
                                                const float* __restrict__ nm,  // [64]
                                                float* __restrict__ out,
                                                int b0grp) {
    const int stride = 4096 * 256;       // 1,048,576 f4 per stripe
    int blk = 4095 - (int)blockIdx.x;
#pragma unroll
    for (int it = 7; it >= 0; --it) {
        int f = blk * 256 + threadIdx.x + it * stride;   // 0..8,388,607
        int b = b0grp + (f >> 18);                       // 256K f4 per b
        size_t e = ((size_t)b << 20) + (((size_t)(f & 0x3FFFF)) << 2);
        int h = (f >> 8) & 1023;
        int i = (f & 255) << 2;
        f4 p4 = *(const f4*)(pw + e);
        f4 x4 = *(const f4*)(x + (b << 10) + i);
        float ps = pre[(b << 10) + h];
        float nb = nm[b];
        f4 o4;
        o4.x = fminf(fmaxf(p4.x + nb * fast_tanh(ps * x4.x), -50.f), 50.f);
        o4.y = fminf(fmaxf(p4.y + nb * fast_tanh(ps * x4.y), -50.f), 50.f);
        o4.z = fminf(fmaxf(p4.z + nb * fast_tanh(ps * x4.z), -50.f), 50.f);
        o4.w = fminf(fmaxf(p4.w + nb * fast_tanh(ps * x4.w), -50.f), 50.f);
        __builtin_nontemporal_store(o4, (f4*)(out + e));
    }
}

extern "C" void kernel_launch(void* const* d_in, const int* in_sizes, int n_in,
                              void* d_out, int out_size, void* d_ws, size_t ws_size,
                              hipStream_t stream) {
    const float* items  = (const float*)d_in[0];
    const float* pw     = (const float*)d_in[1];
    const float* reward = (const float*)d_in[2];
    const float* We     = (const float*)d_in[3];
    const float* be     = (const float*)d_in[4];
    const float* W1     = (const float*)d_in[5];
    const float* b1     = (const float*)d_in[6];
    const float* W2     = (const float*)d_in[7];
    const float* b2     = (const float*)d_in[8];
    const float* Wfc2   = (const float*)d_in[9];
    const float* bfc2   = (const float*)d_in[10];
    const float* Whr    = (const float*)d_in[11];
    const float* bhr    = (const float*)d_in[12];
    const float* Wch    = (const float*)d_in[13];
    const float* bch    = (const float*)d_in[14];
    const float* Wr     = (const float*)d_in[15];
    const float* br     = (const float*)d_in[16];
    const float* Wnm    = (const float*)d_in[17];
    const float* bnm    = (const float*)d_in[18];
    const float* alpha  = (const float*)d_in[19];
    const float* Wv     = (const float*)d_in[20];
    const float* bv     = (const float*)d_in[21];

    float* ws    = (float*)d_ws;
    float* x0    = ws;                // 65536
    float* x1    = ws + 65536;        // 65536
    float* x2    = ws + 131072;       // 65536
    float* preb  = ws + 196608;       // 65536
    float2* parts = (float2*)(ws + 262144);  // 64*128 float2 = 16384 floats

    float* out        = (float*)d_out;
    float* out_choice = out;                        // 64
    float* out_nm     = out + 64;                   // 64
    float* out_value  = out + 128;                  // 64
    float* out_newpw  = out + 192;                  // 67,108,864
    float* out_hidden = out + 192 + BB * HD * HD;   // 65,536

    k_gemm<II><<<512, 1024, 0, stream>>>(items, We, be, x0);
    k_gemm<HD><<<512, 1024, 0, stream>>>(x0, W1, b1, x1);
    k_gemm<HD><<<512, 1024, 0, stream>>>(x1, W2, b2, x2);

    for (int g = 0; g < 2; ++g) {
        int b0 = g * 32;
        k_plastic<<<512, 512, 0, stream>>>(pw, alpha, Wfc2, bfc2, x2, preb, out_hidden, b0);
        k_hrcnm<<<256, 1024, 0, stream>>>(out_hidden, reward, Wr, br, Whr, bhr,
                                          Wnm, parts, b0);
        k_fin<<<32, 256, 0, stream>>>(out_hidden, parts, bnm, Wch, bch, Wv, bv,
                                      out_choice, out_nm, out_value, b0);
        k_update<<<4096, 256, 0, stream>>>(pw, preb, x2, out_nm, out_newpw, b0);
    }
}